// Round 3
// baseline (152.686 us; speedup 1.0000x reference)
//
#include <hip/hip_runtime.h>

// DmvCell RNN scan, B=32, T=2048, D=512. out[b][t] = [mean|var|max] (3*D).
// Memory-bound: 128 MB in + 384 MB out (compulsory), fillBuffer on this chip
// sustains ~7 TB/s -> target ~85-95 us.
//
// R3 design: 3 barrier-free float4 kernels (no LDS):
//  1) agg:   per (float4-chain, 32-step chunk) -> (sum, M2, max) into d_ws
//  2) prefix: per float-chain, serial fold of the 64 chunk aggregates
//             (parallel-variance merge), carry stored IN PLACE in d_ws
//  3) scan:  per (float4-chain, chunk): load carry, exact sequential rescan,
//            stream 3x float4 stores/step (1KB contiguous per wave per store)
// All VMEM is dwordx4; stores never drain mid-kernel. 4096 waves in scan
// (4 waves/SIMD). Falls back to smaller NW (or the proven R2 kernel) if
// ws_size is too small.

#define BB 32
#define TT 2048
#define DD 512
#define NF4 ((BB * DD) / 4)   // 4096 float4 chains
#define NCHAIN (BB * DD)      // 16384 float chains

__device__ __forceinline__ float fast_rcp(float x) {
#if __has_builtin(__builtin_amdgcn_rcpf)
    return __builtin_amdgcn_rcpf(x);
#else
    return 1.0f / x;
#endif
}

// ---------------- kernel 1: per-chunk aggregates ----------------
template <int NW>
__launch_bounds__(256)
__global__ void dmv_agg_kernel(const float* __restrict__ x,
                               float4* __restrict__ ws) {
    constexpr int CHUNK = TT / NW;
    float4* __restrict__ aS  = ws;
    float4* __restrict__ aM2 = ws + (size_t)NW * NF4;
    float4* __restrict__ aMX = ws + 2 * (size_t)NW * NF4;

    const int tid = blockIdx.x * 256 + threadIdx.x;
    const int W   = tid >> 6;       // wave id = c*64 + col
    const int l   = tid & 63;
    const int col = W & 63;         // b*2 + h
    const int c   = W >> 6;         // chunk index
    const int b   = col >> 1, h = col & 1;
    const int chain = col * 64 + l; // global float4-chain index

    const float* xp = x + ((size_t)b * TT + (size_t)c * CHUNK) * DD
                        + h * 256 + l * 4;

    float s[4]  = {0.f, 0.f, 0.f, 0.f};
    float ss[4] = {0.f, 0.f, 0.f, 0.f};
    float mx[4] = {0.f, 0.f, 0.f, 0.f};
    #pragma unroll 8
    for (int k = 0; k < CHUNK; ++k) {
        float4 xv = *(const float4*)(xp + (size_t)k * DD);
        float v[4] = {xv.x, xv.y, xv.z, xv.w};
        #pragma unroll
        for (int j = 0; j < 4; ++j) {
            s[j]  += v[j];
            ss[j]  = fmaf(v[j], v[j], ss[j]);
            mx[j]  = fmaxf(mx[j], v[j]);
        }
    }
    const size_t o = (size_t)c * NF4 + chain;
    aS[o]  = make_float4(s[0], s[1], s[2], s[3]);
    aM2[o] = make_float4(ss[0] - s[0] * s[0] * (1.f / CHUNK),
                         ss[1] - s[1] * s[1] * (1.f / CHUNK),
                         ss[2] - s[2] * s[2] * (1.f / CHUNK),
                         ss[3] - s[3] * s[3] * (1.f / CHUNK));
    aMX[o] = make_float4(mx[0], mx[1], mx[2], mx[3]);
}

// ---------------- kernel 2: in-place prefix fold ----------------
template <int NW>
__launch_bounds__(256)
__global__ void dmv_prefix_kernel(float* __restrict__ ws) {
    constexpr int CHUNK = TT / NW;
    float* __restrict__ aS  = ws;
    float* __restrict__ aM2 = ws + (size_t)NW * NCHAIN;
    float* __restrict__ aMX = ws + 2 * (size_t)NW * NCHAIN;

    const size_t i = (size_t)blockIdx.x * 256 + threadIdx.x;  // float chain

    // c = 0 peeled: carry before chunk 0 is the zero state
    float rs = aS[i], rm2 = aM2[i], rmx = aMX[i];
    aS[i] = 0.f; aM2[i] = 0.f; aMX[i] = 0.f;
    float rn = (float)CHUNK;
    #pragma unroll 8
    for (int c = 1; c < NW; ++c) {
        const size_t idx = (size_t)c * NCHAIN + i;
        float ts = aS[idx], tm2 = aM2[idx], tmx = aMX[idx];
        aS[idx] = rs; aM2[idx] = rm2; aMX[idx] = rmx;   // carry for chunk c
        float n  = rn + (float)CHUNK;
        float da = ts * (1.f / CHUNK) - rs / rn;
        rm2 = rm2 + tm2 + da * da * (rn * (float)CHUNK / n);
        rs += ts;
        rmx = fmaxf(rmx, tmx);
        rn  = n;
    }
}

// ---------------- kernel 3: exact rescan + streaming stores ----------------
template <int NW>
__launch_bounds__(256)
__global__ void dmv_scan_kernel2(const float* __restrict__ x,
                                 const float4* __restrict__ ws,
                                 float* __restrict__ out) {
    constexpr int CHUNK = TT / NW;
    const float4* __restrict__ aS  = ws;
    const float4* __restrict__ aM2 = ws + (size_t)NW * NF4;
    const float4* __restrict__ aMX = ws + 2 * (size_t)NW * NF4;

    const int tid = blockIdx.x * 256 + threadIdx.x;
    const int W   = tid >> 6;
    const int l   = tid & 63;
    const int col = W & 63;
    const int c   = W >> 6;
    const int b   = col >> 1, h = col & 1;
    const int chain = col * 64 + l;

    const size_t o = (size_t)c * NF4 + chain;
    float4 cS = aS[o], cM2 = aM2[o], cMX = aMX[o];

    float rs[4]    = {cS.x, cS.y, cS.z, cS.w};
    float rm2[4]   = {cM2.x, cM2.y, cM2.z, cM2.w};
    float rmx[4]   = {cMX.x, cMX.y, cMX.z, cMX.w};
    float rmean[4];
    float cnt = (float)(c * CHUNK);
    #pragma unroll
    for (int j = 0; j < 4; ++j) rmean[j] = (c > 0) ? rs[j] / cnt : 0.f;

    const float* xp = x + ((size_t)b * TT + (size_t)c * CHUNK) * DD
                        + h * 256 + l * 4;
    float* op = out + ((size_t)b * TT + (size_t)c * CHUNK) * (3 * DD)
                    + h * 256 + l * 4;

    #pragma unroll 8
    for (int k = 0; k < CHUNK; ++k) {
        float4 xv = *(const float4*)(xp + (size_t)k * DD);
        float v[4] = {xv.x, xv.y, xv.z, xv.w};
        cnt += 1.f;
        float inv = fast_rcp(cnt);
        float var[4];
        #pragma unroll
        for (int j = 0; j < 4; ++j) {
            rs[j] += v[j];
            rmx[j] = fmaxf(rmx[j], v[j]);
            float nm = rs[j] * inv;
            rm2[j] += (v[j] - rmean[j]) * (v[j] - nm);
            rmean[j] = nm;
            var[j] = rm2[j] * inv;
        }
        float* row = op + (size_t)k * (3 * DD);
        *(float4*)(row)          = make_float4(rmean[0], rmean[1], rmean[2], rmean[3]);
        *(float4*)(row + DD)     = make_float4(var[0], var[1], var[2], var[3]);
        *(float4*)(row + 2 * DD) = make_float4(rmx[0], rmx[1], rmx[2], rmx[3]);
    }
}

// ---------------- fallback (R2, proven): single kernel, LDS merge ----------
#define FNW 16
#define FCHUNK (TT / FNW)
#define DGRP 64

__launch_bounds__(1024, 1)
__global__ void dmv_scan_fallback(const float* __restrict__ x,
                                  float* __restrict__ out) {
    __shared__ float aggS[FNW][DGRP];
    __shared__ float aggM2[FNW][DGRP];
    __shared__ float aggMX[FNW][DGRP];

    const int tid = threadIdx.x;
    const int w   = tid >> 6;
    const int l   = tid & 63;
    const int b   = blockIdx.x >> 3;
    const int d0  = (blockIdx.x & 7) * DGRP;

    const float* xp = x   + ((size_t)b * TT) * DD + d0 + l
                          + (size_t)(w * FCHUNK) * DD;
    float*       op = out + ((size_t)b * TT) * (3 * DD) + d0 + l
                          + (size_t)(w * FCHUNK) * (3 * DD);

    if (w < FNW - 1) {
        float s = 0.f, ss = 0.f, mx = 0.f;
        #pragma unroll 8
        for (int k = 0; k < FCHUNK; ++k) {
            float xv = xp[(size_t)k * DD];
            s += xv; ss = fmaf(xv, xv, ss); mx = fmaxf(mx, xv);
        }
        aggS[w][l] = s;
        aggM2[w][l] = ss - s * s * (1.0f / FCHUNK);
        aggMX[w][l] = mx;
    }
    __syncthreads();

    float c_n = 0.f, c_s = 0.f, c_m2 = 0.f, c_mx = 0.f;
    for (int j = 0; j < w; ++j) {
        float bs = aggS[j][l], bm2 = aggM2[j][l], bmx = aggMX[j][l];
        if (j == 0) {
            c_n = (float)FCHUNK; c_s = bs; c_m2 = bm2; c_mx = bmx;
        } else {
            float n  = c_n + (float)FCHUNK;
            float da = bs * (1.0f / FCHUNK) - c_s / c_n;
            c_m2 = c_m2 + bm2 + da * da * (c_n * (float)FCHUNK / n);
            c_s += bs; c_mx = fmaxf(c_mx, bmx); c_n = n;
        }
    }

    float cnt = c_n, rs = c_s, rm2 = c_m2, rmx = c_mx;
    float rmean = (w > 0) ? rs / cnt : 0.f;
    #pragma unroll 8
    for (int k = 0; k < FCHUNK; ++k) {
        float xv = xp[(size_t)k * DD];
        cnt += 1.f;
        float inv = fast_rcp(cnt);
        rs += xv; rmx = fmaxf(rmx, xv);
        float nm = rs * inv;
        rm2 += (xv - rmean) * (xv - nm);
        rmean = nm;
        float var = rm2 * inv;
        float* orow = op + (size_t)k * (3 * DD);
        orow[0] = nm; orow[DD] = var; orow[2 * DD] = rmx;
    }
}

// ---------------- launcher ----------------
template <int NW>
static void launch_3k(const float* x, float* out, void* d_ws, hipStream_t stream) {
    float4* ws4 = (float4*)d_ws;
    // agg & scan: 64*NW waves of 64 -> 4096*NW threads -> 16*NW blocks of 256
    dim3 blk(256);
    dmv_agg_kernel<NW><<<dim3(16 * NW), blk, 0, stream>>>(x, ws4);
    dmv_prefix_kernel<NW><<<dim3(NCHAIN / 256), blk, 0, stream>>>((float*)d_ws);
    dmv_scan_kernel2<NW><<<dim3(16 * NW), blk, 0, stream>>>(x, ws4, out);
}

extern "C" void kernel_launch(void* const* d_in, const int* in_sizes, int n_in,
                              void* d_out, int out_size, void* d_ws, size_t ws_size,
                              hipStream_t stream) {
    (void)in_sizes; (void)n_in; (void)out_size;
    const float* x = (const float*)d_in[0];
    float* out = (float*)d_out;

    const size_t need64 = (size_t)3 * 64 * NF4 * sizeof(float4);  // 12.6 MB
    const size_t need32 = (size_t)3 * 32 * NF4 * sizeof(float4);  //  6.3 MB
    const size_t need16 = (size_t)3 * 16 * NF4 * sizeof(float4);  //  3.1 MB

    if (d_ws && ws_size >= need64) {
        launch_3k<64>(x, out, d_ws, stream);
    } else if (d_ws && ws_size >= need32) {
        launch_3k<32>(x, out, d_ws, stream);
    } else if (d_ws && ws_size >= need16) {
        launch_3k<16>(x, out, d_ws, stream);
    } else {
        dmv_scan_fallback<<<dim3(BB * (DD / DGRP)), dim3(1024), 0, stream>>>(x, out);
    }
}

// Round 4
// 133.487 us; speedup vs baseline: 1.1438x; 1.1438x over previous
//
#include <hip/hip_runtime.h>

// DmvCell RNN scan, B=32, T=2048, D=512. out[b][t] = [mean|var|max] (3*D).
// Compulsory traffic: 128 MB in + 402 MB out.
//
// R4 design: per-wave SEQUENTIAL streams. A wave owns (batch b, T-chunk c)
// and ALL of D: input stream = CHUNK x 2KB linear, output stream =
// CHUNK x 6KB linear (6 float4 stores/step, gapless). Lane l carries 8
// chains: d in {4l..4l+3} u {256+4l..256+4l+3}.
//  1) agg:   per (b,c) wave -> (sum, M2, max) per chain into d_ws (cached)
//  2) prefix: per float-chain serial fold over NC chunks (parallel-variance
//             merge); exact carry stored in place
//  3) scan:  load carry, exact sequential rescan, NONTEMPORAL output stores
//            (keeps the 128 MB input L3-resident -> scan re-read off-HBM)
// NC=128 -> 4096 waves (16/CU). Fallback ladder NC=64/32, then proven R2.

#define BB 32
#define TT 2048
#define DD 512
#define NCHAIN (BB * DD)          // 16384 float chains
#define NF4PERB 128               // float4 per row (512 floats)

typedef float f32x4 __attribute__((ext_vector_type(4)));

__device__ __forceinline__ float fast_rcp(float x) {
#if __has_builtin(__builtin_amdgcn_rcpf)
    return __builtin_amdgcn_rcpf(x);
#else
    return 1.0f / x;
#endif
}

__device__ __forceinline__ f32x4 vmax4(f32x4 a, f32x4 b) {
#if __has_builtin(__builtin_elementwise_max)
    return __builtin_elementwise_max(a, b);
#else
    f32x4 r;
    r.x = fmaxf(a.x, b.x); r.y = fmaxf(a.y, b.y);
    r.z = fmaxf(a.z, b.z); r.w = fmaxf(a.w, b.w);
    return r;
#endif
}

__device__ __forceinline__ void nts(f32x4 v, float* p) {
#if __has_builtin(__builtin_nontemporal_store)
    __builtin_nontemporal_store(v, (f32x4*)p);
#else
    *(f32x4*)p = v;
#endif
}

// ---------------- kernel 1: per-chunk aggregates (sequential reads) --------
template <int NC>
__launch_bounds__(256)
__global__ void dmv_agg_kernel(const float* __restrict__ x,
                               f32x4* __restrict__ ws4) {
    constexpr int CHUNK = TT / NC;
    f32x4* __restrict__ aS  = ws4;
    f32x4* __restrict__ aM2 = ws4 + (size_t)NC * 4096;
    f32x4* __restrict__ aMX = ws4 + 2 * (size_t)NC * 4096;

    const int tid = blockIdx.x * 256 + threadIdx.x;
    const int W   = tid >> 6;
    const int l   = tid & 63;
    const int c   = W & (NC - 1);
    const int b   = W / NC;

    const float* xp = x + ((size_t)(b * TT + c * CHUNK)) * DD + 4 * l;

    f32x4 s0 = {0,0,0,0}, s1 = {0,0,0,0};
    f32x4 q0 = {0,0,0,0}, q1 = {0,0,0,0};
    f32x4 m0 = {0,0,0,0}, m1 = {0,0,0,0};
    #pragma unroll 4
    for (int k = 0; k < CHUNK; ++k) {
        f32x4 a = *(const f32x4*)(xp + (size_t)k * DD);
        f32x4 b2 = *(const f32x4*)(xp + (size_t)k * DD + 256);
        s0 += a;  q0 += a * a;   m0 = vmax4(m0, a);
        s1 += b2; q1 += b2 * b2; m1 = vmax4(m1, b2);
    }
    const size_t o = (size_t)c * 4096 + (size_t)b * NF4PERB + l;
    const float ic = 1.0f / (float)CHUNK;
    aS[o]       = s0;  aS[o + 64]  = s1;
    aM2[o]      = q0 - s0 * s0 * ic;
    aM2[o + 64] = q1 - s1 * s1 * ic;
    aMX[o]      = m0;  aMX[o + 64] = m1;
}

// ---------------- kernel 2: in-place prefix fold (per float chain) ---------
template <int NC>
__launch_bounds__(256)
__global__ void dmv_prefix_kernel(float* __restrict__ ws) {
    constexpr int CHUNK = TT / NC;
    float* __restrict__ aS  = ws;
    float* __restrict__ aM2 = ws + (size_t)NC * NCHAIN;
    float* __restrict__ aMX = ws + 2 * (size_t)NC * NCHAIN;

    const int i = blockIdx.x * 256 + threadIdx.x;  // float chain b*512+d

    // c = 0 peeled: carry before chunk 0 is the zero state
    float rs = aS[i], rm2 = aM2[i], rmx = aMX[i];
    aS[i] = 0.f; aM2[i] = 0.f; aMX[i] = 0.f;
    float rn = (float)CHUNK;
    #pragma unroll 8
    for (int c = 1; c < NC; ++c) {
        const size_t idx = (size_t)c * NCHAIN + i;
        float ts = aS[idx], tm2 = aM2[idx], tmx = aMX[idx];
        aS[idx] = rs; aM2[idx] = rm2; aMX[idx] = rmx;   // carry for chunk c
        float n  = rn + (float)CHUNK;
        float da = ts * (1.f / CHUNK) - rs / rn;
        rm2 = rm2 + tm2 + da * da * (rn * (float)CHUNK / n);
        rs += ts;
        rmx = fmaxf(rmx, tmx);
        rn  = n;
    }
}

// ---------------- kernel 3: rescan, sequential nt-store streams ------------
template <int NC>
__launch_bounds__(256)
__global__ void dmv_scan_kernel3(const float* __restrict__ x,
                                 const f32x4* __restrict__ ws4,
                                 float* __restrict__ out) {
    constexpr int CHUNK = TT / NC;
    const f32x4* __restrict__ aS  = ws4;
    const f32x4* __restrict__ aM2 = ws4 + (size_t)NC * 4096;
    const f32x4* __restrict__ aMX = ws4 + 2 * (size_t)NC * 4096;

    const int tid = blockIdx.x * 256 + threadIdx.x;
    const int W   = tid >> 6;
    const int l   = tid & 63;
    const int c   = W & (NC - 1);
    const int b   = W / NC;

    const size_t o = (size_t)c * 4096 + (size_t)b * NF4PERB + l;
    f32x4 rs0 = aS[o],  rs1 = aS[o + 64];
    f32x4 rm20 = aM2[o], rm21 = aM2[o + 64];
    f32x4 rmx0 = aMX[o], rmx1 = aMX[o + 64];

    float cnt = (float)(c * CHUNK);
    f32x4 rmean0 = {0,0,0,0}, rmean1 = {0,0,0,0};
    if (c > 0) {
        float icnt = fast_rcp(cnt);
        rmean0 = rs0 * icnt;
        rmean1 = rs1 * icnt;
    }

    const float* xp = x   + ((size_t)(b * TT + c * CHUNK)) * DD + 4 * l;
    float*       op = out + ((size_t)(b * TT + c * CHUNK)) * (3 * DD) + 4 * l;

    #pragma unroll 4
    for (int k = 0; k < CHUNK; ++k) {
        f32x4 v0 = *(const f32x4*)(xp + (size_t)k * DD);
        f32x4 v1 = *(const f32x4*)(xp + (size_t)k * DD + 256);
        cnt += 1.f;
        float inv = fast_rcp(cnt);
        rs0 += v0; rs1 += v1;
        rmx0 = vmax4(rmx0, v0); rmx1 = vmax4(rmx1, v1);
        f32x4 nm0 = rs0 * inv, nm1 = rs1 * inv;
        rm20 += (v0 - rmean0) * (v0 - nm0);
        rm21 += (v1 - rmean1) * (v1 - nm1);
        rmean0 = nm0; rmean1 = nm1;
        f32x4 var0 = rm20 * inv, var1 = rm21 * inv;
        float* row = op + (size_t)k * (3 * DD);
        nts(nm0,  row);        nts(nm1,  row + 256);
        nts(var0, row + 512);  nts(var1, row + 768);
        nts(rmx0, row + 1024); nts(rmx1, row + 1280);
    }
}

// ---------------- fallback (R2, proven): single kernel, LDS merge ----------
#define FNW 16
#define FCHUNK (TT / FNW)
#define DGRP 64

__launch_bounds__(1024, 1)
__global__ void dmv_scan_fallback(const float* __restrict__ x,
                                  float* __restrict__ out) {
    __shared__ float aggS[FNW][DGRP];
    __shared__ float aggM2[FNW][DGRP];
    __shared__ float aggMX[FNW][DGRP];

    const int tid = threadIdx.x;
    const int w   = tid >> 6;
    const int l   = tid & 63;
    const int b   = blockIdx.x >> 3;
    const int d0  = (blockIdx.x & 7) * DGRP;

    const float* xp = x   + ((size_t)b * TT) * DD + d0 + l
                          + (size_t)(w * FCHUNK) * DD;
    float*       op = out + ((size_t)b * TT) * (3 * DD) + d0 + l
                          + (size_t)(w * FCHUNK) * (3 * DD);

    if (w < FNW - 1) {
        float s = 0.f, ss = 0.f, mx = 0.f;
        #pragma unroll 8
        for (int k = 0; k < FCHUNK; ++k) {
            float xv = xp[(size_t)k * DD];
            s += xv; ss = fmaf(xv, xv, ss); mx = fmaxf(mx, xv);
        }
        aggS[w][l] = s;
        aggM2[w][l] = ss - s * s * (1.0f / FCHUNK);
        aggMX[w][l] = mx;
    }
    __syncthreads();

    float c_n = 0.f, c_s = 0.f, c_m2 = 0.f, c_mx = 0.f;
    for (int j = 0; j < w; ++j) {
        float bs = aggS[j][l], bm2 = aggM2[j][l], bmx = aggMX[j][l];
        if (j == 0) {
            c_n = (float)FCHUNK; c_s = bs; c_m2 = bm2; c_mx = bmx;
        } else {
            float n  = c_n + (float)FCHUNK;
            float da = bs * (1.0f / FCHUNK) - c_s / c_n;
            c_m2 = c_m2 + bm2 + da * da * (c_n * (float)FCHUNK / n);
            c_s += bs; c_mx = fmaxf(c_mx, bmx); c_n = n;
        }
    }

    float cnt = c_n, rs = c_s, rm2 = c_m2, rmx = c_mx;
    float rmean = (w > 0) ? rs / cnt : 0.f;
    #pragma unroll 8
    for (int k = 0; k < FCHUNK; ++k) {
        float xv = xp[(size_t)k * DD];
        cnt += 1.f;
        float inv = fast_rcp(cnt);
        rs += xv; rmx = fmaxf(rmx, xv);
        float nm = rs * inv;
        rm2 += (xv - rmean) * (xv - nm);
        rmean = nm;
        float var = rm2 * inv;
        float* orow = op + (size_t)k * (3 * DD);
        orow[0] = nm; orow[DD] = var; orow[2 * DD] = rmx;
    }
}

// ---------------- launcher ----------------
template <int NC>
static void launch_3k(const float* x, float* out, void* d_ws, hipStream_t stream) {
    dim3 blk(256);
    // agg & scan: 32*NC waves -> 8*NC blocks of 256
    dmv_agg_kernel<NC><<<dim3(8 * NC), blk, 0, stream>>>(x, (f32x4*)d_ws);
    dmv_prefix_kernel<NC><<<dim3(NCHAIN / 256), blk, 0, stream>>>((float*)d_ws);
    dmv_scan_kernel3<NC><<<dim3(8 * NC), blk, 0, stream>>>(x, (const f32x4*)d_ws, out);
}

extern "C" void kernel_launch(void* const* d_in, const int* in_sizes, int n_in,
                              void* d_out, int out_size, void* d_ws, size_t ws_size,
                              hipStream_t stream) {
    (void)in_sizes; (void)n_in; (void)out_size;
    const float* x = (const float*)d_in[0];
    float* out = (float*)d_out;

    const size_t need128 = (size_t)3 * 128 * NCHAIN * sizeof(float);  // 25.2 MB
    const size_t need64  = (size_t)3 * 64  * NCHAIN * sizeof(float);  // 12.6 MB
    const size_t need32  = (size_t)3 * 32  * NCHAIN * sizeof(float);  //  6.3 MB

    if (d_ws && ws_size >= need128) {
        launch_3k<128>(x, out, d_ws, stream);
    } else if (d_ws && ws_size >= need64) {
        launch_3k<64>(x, out, d_ws, stream);
    } else if (d_ws && ws_size >= need32) {
        launch_3k<32>(x, out, d_ws, stream);
    } else {
        dmv_scan_fallback<<<dim3(BB * (DD / DGRP)), dim3(1024), 0, stream>>>(x, out);
    }
}